// Round 4
// baseline (83.963 us; speedup 1.0000x reference)
//
#include <hip/hip_runtime.h>

// PiecewiseChebyshevSeries — R4: MEASUREMENT PROBE.
// Kernel body is byte-identical to R3. kernel_launch launches it 3x
// (idempotent), so  K_kernel = (dur_R4 - dur_R3) / 2  cleanly separates
// kernel time from harness fills/copies/graph-gap overhead that dominates
// dur_us and hides the kernel from rocprof top-5.

constexpr int B = 16;
constexpr int X = 256;
constexpr int Y = 32;
constexpr int N = 131072;

constexpr int THREADS = 256;
constexpr int EPT = 4;                    // elements per thread
constexpr int EPB = THREADS * EPT;        // 1024 elements per block
constexpr int BLOCKS_PER_B = N / EPB;     // 128
constexpr int LSTR = 40;                  // f16 row stride (80 B)

typedef _Float16 half4v __attribute__((ext_vector_type(4)));
typedef _Float16 half8v __attribute__((ext_vector_type(8)));

__device__ __forceinline__ float eval1(const _Float16* __restrict__ lds, float zj)
{
    float u  = zj + 1.0f;
    float xf = floorf(u * 0.5f);
    int   xi = (int)xf;
    float t  = fmaf(-2.0f, xf, u) - 1.0f;

    const half8v* c8 = reinterpret_cast<const half8v*>(lds + xi * LSTR);
    half8v h[4];
    #pragma unroll
    for (int i = 0; i < 4; ++i) h[i] = c8[i];     // 4x ds_read_b128

    float t2  = t + t;
    float Tpp = t;                                 // T1
    float acc = fmaf((float)h[0][1], t, (float)h[0][0]);
    float Tp  = fmaf(t2, t, -1.0f);                // T2
    acc = fmaf((float)h[0][2], Tp, acc);
    #pragma unroll
    for (int m = 3; m < 32; ++m) {
        float Tn = fmaf(t2, Tp, -Tpp);
        acc = fmaf((float)h[m >> 3][m & 7], Tn, acc);
        Tpp = Tp; Tp = Tn;
    }
    return acc;
}

__global__ __launch_bounds__(THREADS, 8)
void cheb_eval(const float* __restrict__ z,
               const float* __restrict__ cheb,
               float* __restrict__ out)
{
    __shared__ __align__(16) _Float16 lds[X * LSTR];   // 20480 B
    const int bid   = blockIdx.x;
    const int b     = bid >> 7;
    const int chunk = bid & 127;
    const int tid   = threadIdx.x;

    const float4* src = reinterpret_cast<const float4*>(cheb + (size_t)b * (X * Y));
    #pragma unroll
    for (int k = 0; k < (X * Y / 4) / THREADS; ++k) {
        int f4  = k * THREADS + tid;
        float4 v = src[f4];
        int row = f4 >> 3;
        int q   = f4 & 7;
        half4v hv = { (_Float16)v.x, (_Float16)v.y, (_Float16)v.z, (_Float16)v.w };
        *reinterpret_cast<half4v*>(&lds[row * LSTR + q * 4]) = hv;
    }
    __syncthreads();

    const float4* zb4 = reinterpret_cast<const float4*>(z   + (size_t)b * N + (size_t)chunk * EPB);
    float4*       ob4 = reinterpret_cast<float4*>      (out + (size_t)b * N + (size_t)chunk * EPB);

    float4 zv = zb4[tid];
    float r0 = eval1(lds, zv.x);
    float r1 = eval1(lds, zv.y);
    float r2 = eval1(lds, zv.z);
    float r3 = eval1(lds, zv.w);
    ob4[tid] = make_float4(r0, r1, r2, r3);
}

extern "C" void kernel_launch(void* const* d_in, const int* in_sizes, int n_in,
                              void* d_out, int out_size, void* d_ws, size_t ws_size,
                              hipStream_t stream) {
    const float* z    = (const float*)d_in[0];
    const float* cheb = (const float*)d_in[1];
    float*       out  = (float*)d_out;
    dim3 grid(B * BLOCKS_PER_B);   // 2048 blocks
    dim3 block(THREADS);
    // 3 identical launches (idempotent): K = (dur - dur_R3)/2.
    hipLaunchKernelGGL(cheb_eval, grid, block, 0, stream, z, cheb, out);
    hipLaunchKernelGGL(cheb_eval, grid, block, 0, stream, z, cheb, out);
    hipLaunchKernelGGL(cheb_eval, grid, block, 0, stream, z, cheb, out);
}